// Round 9
// baseline (491.974 us; speedup 1.0000x reference)
//
#include <hip/hip_runtime.h>
#include <math.h>

// ---------------------------------------------------------------------------
// R9 = R5 (passing, 489us) + conv3 on 32x32x16 MFMA, with the R6-R8 work-
// partition bug FIXED: each block tile is M=128 x N=128 = 16 wave-tiles of
// 32x32; 4 waves each own a 2x2 tile grid (mh=wv&1 -> mtiles, nh=wv>>1 ->
// ntiles). R6-R8 only covered 8/16 tiles (oc 64..127 never written).
// Everything else (conv1, conv2 16x16, mfma_res, prevq) is R5 verbatim.
// ws layout:
//   shorts @0: repW2 393216, repW3 @393216 (442368), repR1 @835584 (110592),
//              repR2 @946176 (110592), repP1 @1056768 (12288), repP2 @1069056
//   floats:  B @4194304 : conv2 out / h' [16,128,64,64]
//            A @12582912: conv1 half-out [8,64,128,128] -> h [16,128,64,64]
// ---------------------------------------------------------------------------

typedef short v8s  __attribute__((ext_vector_type(8)));
typedef float v4f  __attribute__((ext_vector_type(4)));
typedef float v16f __attribute__((ext_vector_type(16)));

#define B_OFF 4194304
#define A_OFF 12582912
#define W2_S 0
#define W3_S 393216
#define WR1_S 835584
#define WR2_S 946176
#define WP1_S 1056768
#define WP2_S 1069056

// 3-limb bf16 truncation decomposition: x = h+m+l + O(2^-24 |x|)
__device__ inline void limb3(float v, unsigned short& h, unsigned short& m,
                             unsigned short& l) {
    unsigned ub = __float_as_uint(v);
    unsigned hb = ub & 0xffff0000u;
    float r1 = v - __uint_as_float(hb);
    unsigned mb = __float_as_uint(r1) & 0xffff0000u;
    float r2 = r1 - __uint_as_float(mb);
    unsigned lb = __float_as_uint(r2) & 0xffff0000u;
    h = (unsigned short)(hb >> 16);
    m = (unsigned short)(mb >> 16);
    l = (unsigned short)(lb >> 16);
}

// ----- conv configs ---------------------------------------------------------
struct CfgConv2 {   // 4x4 s2 p1 as stride-1 conv over 4 phase planes (16x16)
    static constexpr int NC = 8, NT = 4, OC = 128, ICG = 64, IN_H = 128, IN_W = 128;
    static constexpr bool RELU_IN = false, RELU_OUT = true;
    __device__ static void tap(int c, int t, int& ry, int& rx) {
        int py = (c >> 2) & 1, px = (c >> 1) & 1;
        ry = (t >> 1) - py; rx = (t & 1) - px;
    }
    __device__ static void inaddr(int c, int oy, int r, int X,
                                  int& Yg, int& Xg, int& ic0) {
        int py = (c >> 2) & 1, px = (c >> 1) & 1;
        Yg = 2 * (oy + r - 1) + py; Xg = 2 * X + px; ic0 = (c & 1) * 32;
    }
    __device__ static int widx(int c, int t, int oc, int ic) {
        int py = (c >> 2) & 1, px = (c >> 1) & 1, half = c & 1;
        int dy = 2 * (t >> 1) + (1 - py), dx = 2 * (t & 1) + (1 - px);
        return ((oc * 64 + half * 32 + ic) * 4 + dy) * 4 + dx;
    }
};
struct CfgConv3 {   // 3x3 s1 p1, 128->128 : 32x32x16 2-row path
    static constexpr int ROWS = 2, NC = 4, NT = 9, OC = 128;
    static constexpr int CH_STRIDE = 4096;
    static constexpr bool RELU_OUT = false;
    static constexpr int MINW = 2;
    __device__ static void tap(int c, int t, int& ry, int& rx) {
        ry = t / 3 - 1; rx = t % 3 - 1;
    }
    __device__ static int gaddr(int n, int c, int icp, int Yg, int X) {
        return ((n * 128 + c * 32 + 2 * icp) * 64 + Yg) * 64 + X;
    }
    __device__ static int widx(int c, int t, int oc, int ic) {
        return ((oc * 128 + c * 32 + ic) * 3 + t / 3) * 3 + t % 3;
    }
};
struct CfgRes {     // 3x3 s1 p1, relu(in), 128->32 (16x16 path)
    static constexpr int NC = 4, NT = 9, OC = 32;
    __device__ static int widx(int c, int t, int oc, int ic) {
        return ((oc * 128 + c * 32 + ic) * 3 + t / 3) * 3 + t % 3;
    }
};
struct Cfg1x1 {     // 1x1, 32->128 (16x16 path)
    static constexpr int NC = 1, NT = 1, OC = 128;
    __device__ static int widx(int c, int t, int oc, int ic) {
        return oc * 32 + ic;
    }
};

// ----- weight repacks -------------------------------------------------------
// 16x16 B-frag layout: dst[(((ct*3+L)*NTILE + nt)<<9) + (q*16+o)*8+j]
template <typename C>
__device__ inline void repack_one(const float* __restrict__ w,
                                  short* __restrict__ dst, int idx) {
    int s  = idx & 31;
    int oc = (idx >> 5) % C::OC;
    int ct = idx / (32 * C::OC);
    int c = ct / C::NT, t = ct % C::NT;
    float val = w[C::widx(c, t, oc, s)];
    unsigned short h, m, l;
    limb3(val, h, m, l);
    constexpr int NTILE = C::OC / 16;
    int nt = oc >> 4, o = oc & 15, q = s >> 3, j = s & 7;
    int fr = ((q * 16 + o) << 3) + j;
    dst[(((ct * 3 + 0) * NTILE + nt) << 9) + fr] = (short)h;
    dst[(((ct * 3 + 1) * NTILE + nt) << 9) + fr] = (short)m;
    dst[(((ct * 3 + 2) * NTILE + nt) << 9) + fr] = (short)l;
}
// 32x32 B-frag layout: n=lane&31 -> oc, k=(lane>>5)*8+j, split over kh tiles
template <typename C>
__device__ inline void repack_one32(const float* __restrict__ w,
                                    short* __restrict__ dst, int idx) {
    int s  = idx & 31;
    int oc = (idx >> 5) % C::OC;
    int ct = idx / (32 * C::OC);
    int c = ct / C::NT, t = ct % C::NT;
    float val = w[C::widx(c, t, oc, s)];
    unsigned short h, m, l;
    limb3(val, h, m, l);
    constexpr int NTX = C::OC / 32;
    int nt = oc >> 5, kh = s >> 4, h8 = (s >> 3) & 1, j = s & 7;
    int fr = (((h8 << 5) + (oc & 31)) << 3) + j;
    dst[((((ct * 3 + 0) * NTX + nt) * 2 + kh) << 9) + fr] = (short)h;
    dst[((((ct * 3 + 1) * NTX + nt) * 2 + kh) << 9) + fr] = (short)m;
    dst[((((ct * 3 + 2) * NTX + nt) * 2 + kh) << 9) + fr] = (short)l;
}

__global__ __launch_bounds__(256) void repack_all_k(
    const float* __restrict__ w2, const float* __restrict__ w3,
    const float* __restrict__ r1, const float* __restrict__ r2,
    const float* __restrict__ p1, const float* __restrict__ p2,
    short* __restrict__ base)
{
    int idx = blockIdx.x * 256 + threadIdx.x;
    if (idx < 131072) { repack_one<CfgConv2>(w2, base + W2_S, idx); return; }
    idx -= 131072;
    if (idx < 147456) { repack_one32<CfgConv3>(w3, base + W3_S, idx); return; }
    idx -= 147456;
    if (idx < 36864)  { repack_one<CfgRes>(r1, base + WR1_S, idx); return; }
    idx -= 36864;
    if (idx < 36864)  { repack_one<CfgRes>(r2, base + WR2_S, idx); return; }
    idx -= 36864;
    if (idx < 4096)   { repack_one<Cfg1x1>(p1, base + WP1_S, idx); return; }
    idx -= 4096;
    if (idx < 4096)   { repack_one<Cfg1x1>(p2, base + WP2_S, idx); }
}

// ----- pipelined 16x16x32 MFMA implicit-GEMM conv (R5 verbatim) -------------
template <typename C>
__global__ __launch_bounds__(256, 3) void mfma_conv(
    const float* __restrict__ in, const short* __restrict__ repw,
    const float* __restrict__ bias, float* __restrict__ out, int n0)
{
    constexpr int APLANE = 3 * 66 * 32;        // shorts; dwords 3168
    constexpr int NTILE  = C::OC / 16;
    __shared__ __align__(16) short lA[3 * APLANE];

    int tid = threadIdx.x;
    int lane = tid & 63, wv = tid >> 6;
    int n_img = blockIdx.x >> 6, oy = blockIdx.x & 63;

    for (int idx = tid; idx < 3 * 3 * 2 * 16; idx += 256) {
        int plane = idx / 96;
        int rem = idx % 96;
        int rr = rem / 32;
        int hc = (rem / 16) & 1;
        int d = idx & 15;
        ((unsigned*)lA)[plane * 3168 + (rr * 66 + hc * 65) * 16 + d] = 0;
    }

    v4f acc[4][2] = {};
    int nbase = wv * 2;
    int Xq = tid & 15, icp = tid >> 4, quad = lane >> 4;

    float pv[24];
    auto issue_loads = [&](int c) {
#pragma unroll
        for (int it = 0; it < 12; it++) {
            int r = it >> 2, xg = it & 3;
            int X = xg * 16 + Xq;
            int Yg, Xg, ic0;
            C::inaddr(c, oy, r, X, Yg, Xg, ic0);
            float v0 = 0.f, v1 = 0.f;
            if (Yg >= 0 && Yg < C::IN_H) {
                int g = ((n_img * C::ICG + ic0 + 2 * icp) * C::IN_H + Yg) * C::IN_W + Xg;
                v0 = in[g];
                v1 = in[g + C::IN_H * C::IN_W];
            }
            pv[2 * it] = v0; pv[2 * it + 1] = v1;
        }
    };
    auto load_bf = [&](int c, int t, v8s (&dst)[2][3]) {
#pragma unroll
        for (int nt = 0; nt < 2; nt++)
#pragma unroll
            for (int L = 0; L < 3; L++)
                dst[nt][L] = *(const v8s*)(repw +
                    ((((c * C::NT + t) * 3 + L) * NTILE + (nbase + nt)) << 9) +
                    (lane << 3));
    };

    issue_loads(0);

    for (int c = 0; c < C::NC; c++) {
        __syncthreads();
#pragma unroll
        for (int it = 0; it < 12; it++) {
            int r = it >> 2, xg = it & 3;
            int X = xg * 16 + Xq;
            float v0 = pv[2 * it], v1 = pv[2 * it + 1];
            if constexpr (C::RELU_IN) { v0 = fmaxf(v0, 0.f); v1 = fmaxf(v1, 0.f); }
            unsigned short h0, m0, l0, h1, m1, l1;
            limb3(v0, h0, m0, l0);
            limb3(v1, h1, m1, l1);
            int cell = r * 66 + X + 1;
            int f = (cell + (cell >> 2)) & 3;
            int phys = (icp & 3) + 4 * (((icp >> 2) + f) & 3);
            unsigned* pa = (unsigned*)lA + cell * 16 + phys;
            pa[0]        = (unsigned)h0 | ((unsigned)h1 << 16);
            pa[3168]     = (unsigned)m0 | ((unsigned)m1 << 16);
            pa[2 * 3168] = (unsigned)l0 | ((unsigned)l1 << 16);
        }
        __syncthreads();
        if (c + 1 < C::NC) issue_loads(c + 1);

        v8s bf[2][2][3];
        load_bf(c, 0, bf[0]);
#pragma unroll
        for (int t = 0; t < C::NT; t++) {
            constexpr int NTT = C::NT;
            if (t + 1 < NTT) load_bf(c, t + 1, bf[(t + 1) & 1]);
            int ry, rx;
            C::tap(c, t, ry, rx);
#pragma unroll
            for (int mt = 0; mt < 4; mt++) {
                int x = mt * 16 + (lane & 15);
                int cell = (ry + 1) * 66 + (x + rx + 1);
                int f = (cell + (cell >> 2)) & 3;
                int aa = cell * 32 + (((quad + f) & 3) << 3);
                v8s ah = *(const v8s*)&lA[aa];
                v8s am = *(const v8s*)&lA[APLANE + aa];
                v8s al = *(const v8s*)&lA[2 * APLANE + aa];
#pragma unroll
                for (int nt = 0; nt < 2; nt++) {
                    v4f a0 = acc[mt][nt];
                    a0 = __builtin_amdgcn_mfma_f32_16x16x32_bf16(ah, bf[t & 1][nt][0], a0, 0, 0, 0);
                    a0 = __builtin_amdgcn_mfma_f32_16x16x32_bf16(ah, bf[t & 1][nt][1], a0, 0, 0, 0);
                    a0 = __builtin_amdgcn_mfma_f32_16x16x32_bf16(am, bf[t & 1][nt][0], a0, 0, 0, 0);
                    a0 = __builtin_amdgcn_mfma_f32_16x16x32_bf16(am, bf[t & 1][nt][1], a0, 0, 0, 0);
                    a0 = __builtin_amdgcn_mfma_f32_16x16x32_bf16(ah, bf[t & 1][nt][2], a0, 0, 0, 0);
                    a0 = __builtin_amdgcn_mfma_f32_16x16x32_bf16(al, bf[t & 1][nt][0], a0, 0, 0, 0);
                    acc[mt][nt] = a0;
                }
            }
        }
    }
#pragma unroll
    for (int mt = 0; mt < 4; mt++) {
        int x0 = mt * 16 + quad * 4;
#pragma unroll
        for (int nt = 0; nt < 2; nt++) {
            int oc = (nbase + nt) * 16 + (lane & 15);
            float bv = bias[oc];
            float v0 = acc[mt][nt][0] + bv;
            float v1 = acc[mt][nt][1] + bv;
            float v2 = acc[mt][nt][2] + bv;
            float v3 = acc[mt][nt][3] + bv;
            if constexpr (C::RELU_OUT) {
                v0 = fmaxf(v0, 0.f); v1 = fmaxf(v1, 0.f);
                v2 = fmaxf(v2, 0.f); v3 = fmaxf(v3, 0.f);
            }
            float4 o = make_float4(v0, v1, v2, v3);
            *(float4*)&out[(((n0 + n_img) * C::OC + oc) * 64 + oy) * 64 + x0] = o;
        }
    }
}

// ----- 32x32x16 MFMA conv, 2-row blocks, FIXED partition --------------------
// Block tile: M=128 (2 rows x 64 x) x N=128 oc = 16 tiles of 32x32.
// Wave wv: m-half mh=wv&1 (mtiles mh*2+{0,1}), n-half nh=wv>>1
// (ntiles nh*2+{0,1}) -> acc[2][2], 4 waves x 4 tiles = full coverage.
template <typename C>
__global__ __launch_bounds__(256, C::MINW) void mfma_conv32(
    const float* __restrict__ in, const short* __restrict__ repw,
    const float* __restrict__ bias, float* __restrict__ out, int n0)
{
    constexpr int R   = C::ROWS;               // 2
    constexpr int SR  = R + 2;                 // 4
    constexpr int ADW = SR * 66 * 16;          // dwords per limb plane
    constexpr int APL = ADW * 2;               // shorts per plane
    constexpr int NTX = C::OC / 32;            // 4
    constexpr int BPI = 64 / R;                // 32
    __shared__ __align__(16) short lA[3 * APL];

    int tid = threadIdx.x;
    int lane = tid & 63, wv = tid >> 6;
    int n_img = blockIdx.x / BPI, oyb = (blockIdx.x % BPI) * R;
    int mh = wv & 1, nh = wv >> 1;

    for (int idx = tid; idx < 3 * SR * 2 * 16; idx += 256) {
        int d = idx & 15, t1 = idx >> 4;
        int hc = t1 & 1, t2 = t1 >> 1;
        int rr = t2 % SR, plane = t2 / SR;
        ((unsigned*)lA)[plane * ADW + (rr * 66 + hc * 65) * 16 + d] = 0;
    }

    v16f acc[2][2] = {};                       // [mi][ni]
    int Xq = tid & 15, icp = tid >> 4;

    float pv[8 * SR];
    auto issue_loads = [&](int c) {
#pragma unroll
        for (int it = 0; it < 4 * SR; it++) {
            int r = it >> 2, xg = it & 3;
            int X = xg * 16 + Xq;
            int Yg = oyb + r - 1;
            float v0 = 0.f, v1 = 0.f;
            if (Yg >= 0 && Yg < 64) {
                int g = C::gaddr(n_img, c, icp, Yg, X);
                v0 = in[g];
                v1 = in[g + C::CH_STRIDE];
            }
            pv[2 * it] = v0; pv[2 * it + 1] = v1;
        }
    };

    issue_loads(0);

    for (int c = 0; c < C::NC; c++) {
        __syncthreads();
#pragma unroll
        for (int it = 0; it < 4 * SR; it++) {
            int r = it >> 2, xg = it & 3;
            int X = xg * 16 + Xq;
            float v0 = pv[2 * it], v1 = pv[2 * it + 1];
            unsigned short h0, m0, l0, h1, m1, l1;
            limb3(v0, h0, m0, l0);
            limb3(v1, h1, m1, l1);
            int cell = r * 66 + X + 1;
            int f = (cell + (cell >> 2)) & 3;
            int phys = (icp & 3) + 4 * (((icp >> 2) + f) & 3);
            unsigned* pa = (unsigned*)lA + cell * 16 + phys;
            pa[0]       = (unsigned)h0 | ((unsigned)h1 << 16);
            pa[ADW]     = (unsigned)m0 | ((unsigned)m1 << 16);
            pa[2 * ADW] = (unsigned)l0 | ((unsigned)l1 << 16);
        }
        __syncthreads();
        if (c + 1 < C::NC) issue_loads(c + 1);

#pragma unroll
        for (int t = 0; t < C::NT; t++) {
            int ry, rx;
            C::tap(c, t, ry, rx);
            // B fragments for both ntiles (global, per-lane repacked, L1-hot)
            v8s bh[2][2], bm[2][2], bl[2][2];  // [ni][kh]
#pragma unroll
            for (int ni = 0; ni < 2; ni++)
#pragma unroll
            for (int kh = 0; kh < 2; kh++) {
                const short* bp = repw +
                    (((((c * C::NT + t) * 3 + 0) * NTX + nh * 2 + ni) * 2 + kh) << 9) +
                    (lane << 3);
                bh[ni][kh] = *(const v8s*)bp;
                bm[ni][kh] = *(const v8s*)(bp + ((NTX * 2) << 9));
                bl[ni][kh] = *(const v8s*)(bp + ((NTX * 2) << 10));
            }
#pragma unroll
            for (int mi = 0; mi < 2; mi++) {
                int x = mi * 32 + (lane & 31);
                int cell = (mh + ry + 1) * 66 + x + rx + 1;
                int f = (cell + (cell >> 2)) & 3;
                v8s ah[2], am[2], al[2];
#pragma unroll
                for (int kh = 0; kh < 2; kh++) {
                    int g = kh * 2 + (lane >> 5);
                    int aa = cell * 32 + (((g + f) & 3) << 3);
                    ah[kh] = *(const v8s*)&lA[aa];
                    am[kh] = *(const v8s*)&lA[APL + aa];
                    al[kh] = *(const v8s*)&lA[2 * APL + aa];
                }
#pragma unroll
                for (int ni = 0; ni < 2; ni++) {
                    v16f a0 = acc[mi][ni];
#pragma unroll
                    for (int kh = 0; kh < 2; kh++) {
                        a0 = __builtin_amdgcn_mfma_f32_32x32x16_bf16(ah[kh], bh[ni][kh], a0, 0, 0, 0);
                        a0 = __builtin_amdgcn_mfma_f32_32x32x16_bf16(ah[kh], bm[ni][kh], a0, 0, 0, 0);
                        a0 = __builtin_amdgcn_mfma_f32_32x32x16_bf16(am[kh], bh[ni][kh], a0, 0, 0, 0);
                        a0 = __builtin_amdgcn_mfma_f32_32x32x16_bf16(am[kh], bm[ni][kh], a0, 0, 0, 0);
                        a0 = __builtin_amdgcn_mfma_f32_32x32x16_bf16(ah[kh], bl[ni][kh], a0, 0, 0, 0);
                        a0 = __builtin_amdgcn_mfma_f32_32x32x16_bf16(al[kh], bh[ni][kh], a0, 0, 0, 0);
                    }
                    acc[mi][ni] = a0;
                }
            }
        }
    }
    // epilogue: C/D col=lane&31 (oc), tile row=(reg&3)+8*(reg>>2)+4*(lane>>5)
    {
        int row = oyb + mh;
#pragma unroll
        for (int ni = 0; ni < 2; ni++) {
            int oc = (nh * 2 + ni) * 32 + (lane & 31);
            float bv = bias[oc];
#pragma unroll
            for (int mi = 0; mi < 2; mi++) {
#pragma unroll
                for (int rg = 0; rg < 4; rg++) {
                    int x0 = mi * 32 + rg * 8 + (lane >> 5) * 4;
                    float v0 = acc[mi][ni][rg * 4 + 0] + bv;
                    float v1 = acc[mi][ni][rg * 4 + 1] + bv;
                    float v2 = acc[mi][ni][rg * 4 + 2] + bv;
                    float v3 = acc[mi][ni][rg * 4 + 3] + bv;
                    if constexpr (C::RELU_OUT) {
                        v0 = fmaxf(v0, 0.f); v1 = fmaxf(v1, 0.f);
                        v2 = fmaxf(v2, 0.f); v3 = fmaxf(v3, 0.f);
                    }
                    float4 o = make_float4(v0, v1, v2, v3);
                    *(float4*)&out[(((n0 + n_img) * C::OC + oc) * 64 + row) * 64 + x0] = o;
                }
            }
        }
    }
}

// ----- fused residual block (16x16 path, R5 verbatim) -----------------------
__global__ __launch_bounds__(256, 4) void mfma_res(
    const float* __restrict__ in, const short* __restrict__ repw,
    const float* __restrict__ b1, const short* __restrict__ repp,
    const float* __restrict__ b2, float* __restrict__ out)
{
    constexpr int APLANE = 3 * 66 * 32;
    __shared__ __align__(16) short lA[3 * APLANE];

    int tid = threadIdx.x;
    int lane = tid & 63, wv = tid >> 6;
    int n_img = blockIdx.x >> 6, oy = blockIdx.x & 63;

    for (int idx = tid; idx < 3 * 3 * 2 * 16; idx += 256) {
        int plane = idx / 96;
        int rem = idx % 96;
        int rr = rem / 32;
        int hc = (rem / 16) & 1;
        int d = idx & 15;
        ((unsigned*)lA)[plane * 3168 + (rr * 66 + hc * 65) * 16 + d] = 0;
    }

    v4f acc[2] = {};
    int Xq = tid & 15, icp = tid >> 4, quad = lane >> 4;

    float pv[24];
    auto issue_loads = [&](int c) {
#pragma unroll
        for (int it = 0; it < 12; it++) {
            int r = it >> 2, xg = it & 3;
            int X = xg * 16 + Xq;
            int Yg = oy + r - 1;
            float v0 = 0.f, v1 = 0.f;
            if (Yg >= 0 && Yg < 64) {
                int g = ((n_img * 128 + c * 32 + 2 * icp) * 64 + Yg) * 64 + X;
                v0 = in[g];
                v1 = in[g + 4096];
            }
            pv[2 * it] = v0; pv[2 * it + 1] = v1;
        }
    };

    issue_loads(0);

    for (int c = 0; c < 4; c++) {
        __syncthreads();
#pragma unroll
        for (int it = 0; it < 12; it++) {
            int r = it >> 2, xg = it & 3;
            int X = xg * 16 + Xq;
            float v0 = fmaxf(pv[2 * it], 0.f);
            float v1 = fmaxf(pv[2 * it + 1], 0.f);
            unsigned short h0, m0, l0, h1, m1, l1;
            limb3(v0, h0, m0, l0);
            limb3(v1, h1, m1, l1);
            int cell = r * 66 + X + 1;
            int f = (cell + (cell >> 2)) & 3;
            int phys = (icp & 3) + 4 * (((icp >> 2) + f) & 3);
            unsigned* pa = (unsigned*)lA + cell * 16 + phys;
            pa[0]        = (unsigned)h0 | ((unsigned)h1 << 16);
            pa[3168]     = (unsigned)m0 | ((unsigned)m1 << 16);
            pa[2 * 3168] = (unsigned)l0 | ((unsigned)l1 << 16);
        }
        __syncthreads();
        if (c + 1 < 4) issue_loads(c + 1);

        v8s bf[2][2][3];
        auto load_bf = [&](int t, v8s (&dst)[2][3]) {
#pragma unroll
            for (int nt = 0; nt < 2; nt++)
#pragma unroll
                for (int L = 0; L < 3; L++)
                    dst[nt][L] = *(const v8s*)(repw +
                        ((((c * 9 + t) * 3 + L) * 2 + nt) << 9) + (lane << 3));
        };
        load_bf(0, bf[0]);
#pragma unroll
        for (int t = 0; t < 9; t++) {
            if (t + 1 < 9) load_bf(t + 1, bf[(t + 1) & 1]);
            int ry = t / 3 - 1, rx = t % 3 - 1;
            int x = wv * 16 + (lane & 15);
            int cell = (ry + 1) * 66 + (x + rx + 1);
            int f = (cell + (cell >> 2)) & 3;
            int aa = cell * 32 + (((quad + f) & 3) << 3);
            v8s ah = *(const v8s*)&lA[aa];
            v8s am = *(const v8s*)&lA[APLANE + aa];
            v8s al = *(const v8s*)&lA[2 * APLANE + aa];
#pragma unroll
            for (int nt = 0; nt < 2; nt++) {
                v4f a0 = acc[nt];
                a0 = __builtin_amdgcn_mfma_f32_16x16x32_bf16(ah, bf[t & 1][nt][0], a0, 0, 0, 0);
                a0 = __builtin_amdgcn_mfma_f32_16x16x32_bf16(ah, bf[t & 1][nt][1], a0, 0, 0, 0);
                a0 = __builtin_amdgcn_mfma_f32_16x16x32_bf16(am, bf[t & 1][nt][0], a0, 0, 0, 0);
                a0 = __builtin_amdgcn_mfma_f32_16x16x32_bf16(am, bf[t & 1][nt][1], a0, 0, 0, 0);
                a0 = __builtin_amdgcn_mfma_f32_16x16x32_bf16(ah, bf[t & 1][nt][2], a0, 0, 0, 0);
                a0 = __builtin_amdgcn_mfma_f32_16x16x32_bf16(al, bf[t & 1][nt][0], a0, 0, 0, 0);
                acc[nt] = a0;
            }
        }
    }

    __syncthreads();
#pragma unroll
    for (int nt = 0; nt < 2; nt++) {
        int ic = nt * 16 + (lane & 15);
        int icp2 = ic >> 1, hilo = ic & 1;
        float bv = b1[ic];
#pragma unroll
        for (int r = 0; r < 4; r++) {
            int x = wv * 16 + quad * 4 + r;
            float v = fmaxf(acc[nt][r] + bv, 0.f);
            unsigned short h, m, l;
            limb3(v, h, m, l);
            int f = (x + (x >> 2)) & 3;
            int phys = (icp2 & 3) + 4 * (((icp2 >> 2) + f) & 3);
            int sa = x * 32 + phys * 2 + hilo;
            lA[sa] = (short)h;
            lA[2048 + sa] = (short)m;
            lA[4096 + sa] = (short)l;
        }
    }
    __syncthreads();

    v4f a2[8] = {};
    {
        int x = wv * 16 + (lane & 15);
        int f = (x + (x >> 2)) & 3;
        int aa = x * 32 + (((quad + f) & 3) << 3);
        v8s ah = *(const v8s*)&lA[aa];
        v8s am = *(const v8s*)&lA[2048 + aa];
        v8s al = *(const v8s*)&lA[4096 + aa];
#pragma unroll
        for (int nt = 0; nt < 8; nt++) {
            v8s bh = *(const v8s*)(repp + ((0 * 8 + nt) << 9) + (lane << 3));
            v8s bm = *(const v8s*)(repp + ((1 * 8 + nt) << 9) + (lane << 3));
            v8s bl = *(const v8s*)(repp + ((2 * 8 + nt) << 9) + (lane << 3));
            v4f a0 = a2[nt];
            a0 = __builtin_amdgcn_mfma_f32_16x16x32_bf16(ah, bh, a0, 0, 0, 0);
            a0 = __builtin_amdgcn_mfma_f32_16x16x32_bf16(ah, bm, a0, 0, 0, 0);
            a0 = __builtin_amdgcn_mfma_f32_16x16x32_bf16(am, bh, a0, 0, 0, 0);
            a0 = __builtin_amdgcn_mfma_f32_16x16x32_bf16(am, bm, a0, 0, 0, 0);
            a0 = __builtin_amdgcn_mfma_f32_16x16x32_bf16(ah, bl, a0, 0, 0, 0);
            a0 = __builtin_amdgcn_mfma_f32_16x16x32_bf16(al, bh, a0, 0, 0, 0);
            a2[nt] = a0;
        }
    }
#pragma unroll
    for (int nt = 0; nt < 8; nt++) {
        int oc = nt * 16 + (lane & 15);
        int x0 = wv * 16 + quad * 4;
        int off = ((n_img * 128 + oc) * 64 + oy) * 64 + x0;
        float4 hv = *(const float4*)&in[off];
        float bv = b2[oc];
        float4 o = make_float4(hv.x + a2[nt][0] + bv, hv.y + a2[nt][1] + bv,
                               hv.z + a2[nt][2] + bv, hv.w + a2[nt][3] + bv);
        *(float4*)&out[off] = o;
    }
}

// ----- conv1: [8,1,256,256] -> [8,64,128,128], 4x4 s2 p1, relu (R5) ---------
__global__ __launch_bounds__(256) void conv1_k(
    const float* __restrict__ x, const float* __restrict__ w,
    const float* __restrict__ b, float* __restrict__ out)
{
    int tid = blockIdx.x * 256 + threadIdx.x;     // 131072
    int n   = tid >> 14;
    int rem = tid & 16383;
    int oy  = rem >> 7;
    int ox  = rem & 127;
    int iy0 = oy * 2 - 1, ix0 = ox * 2 - 1;
    const float* xb = x + n * 65536;
    float v[16];
#pragma unroll
    for (int ky = 0; ky < 4; ky++) {
#pragma unroll
        for (int kx = 0; kx < 4; kx++) {
            int iy = iy0 + ky, ix = ix0 + kx;
            bool ok = (iy >= 0) & (iy < 256) & (ix >= 0) & (ix < 256);
            v[ky * 4 + kx] = ok ? xb[iy * 256 + ix] : 0.f;
        }
    }
    int obase = (n * 64) * 16384 + (oy << 7) + ox;
    for (int oc = 0; oc < 64; oc++) {
        float acc = b[oc];
        const float* wp = w + oc * 16;
#pragma unroll
        for (int k = 0; k < 16; k++) acc = fmaf(v[k], wp[k], acc);
        out[obase + oc * 16384] = fmaxf(acc, 0.f);
    }
}

// ----- fused 1x1 projection + cosine VQ (R5 verbatim) -----------------------
__global__ __launch_bounds__(256) void prevq_k(
    const float* __restrict__ h, const float* __restrict__ wpre,
    const float* __restrict__ bpre, const float* __restrict__ cb,
    float* __restrict__ out)
{
    __shared__ float4 en[2048];
    for (int i = threadIdx.x; i < 2048; i += 256) {
        float c0 = cb[i * 4 + 0], c1 = cb[i * 4 + 1];
        float c2 = cb[i * 4 + 2], c3 = cb[i * 4 + 3];
        float nrm = sqrtf(c0 * c0 + c1 * c1 + c2 * c2 + c3 * c3) + 1e-12f;
        en[i] = make_float4(c0 / nrm, c1 / nrm, c2 / nrm, c3 / nrm);
    }
    __syncthreads();

    int tid = blockIdx.x * 256 + threadIdx.x;     // 65536
    int n   = tid >> 12;
    int pos = tid & 4095;
    const float* hb = h + n * 128 * 4096 + pos;
    float z0 = bpre[0], z1 = bpre[1], z2 = bpre[2], z3 = bpre[3];
    for (int ic = 0; ic < 128; ic++) {
        float v = fmaxf(hb[ic * 4096], 0.f);
        z0 = fmaf(v, wpre[ic],       z0);
        z1 = fmaf(v, wpre[128 + ic], z1);
        z2 = fmaf(v, wpre[256 + ic], z2);
        z3 = fmaf(v, wpre[384 + ic], z3);
    }
    float best = -1e30f;
    int   bidx = 0;
    for (int k = 0; k < 2048; k++) {
        float4 e = en[k];
        float s = z0 * e.x + z1 * e.y + z2 * e.z + z3 * e.w;
        if (s > best) { best = s; bidx = k; }
    }
    const float* q = cb + bidx * 4;
    out[(n * 4 + 0) * 4096 + pos] = q[0];
    out[(n * 4 + 1) * 4096 + pos] = q[1];
    out[(n * 4 + 2) * 4096 + pos] = q[2];
    out[(n * 4 + 3) * 4096 + pos] = q[3];
}

extern "C" void kernel_launch(void* const* d_in, const int* in_sizes, int n_in,
                              void* d_out, int out_size, void* d_ws, size_t ws_size,
                              hipStream_t stream)
{
    const float* x    = (const float*)d_in[0];
    const float* w1   = (const float*)d_in[1];
    const float* b1   = (const float*)d_in[2];
    const float* w2   = (const float*)d_in[3];
    const float* b2   = (const float*)d_in[4];
    const float* w3   = (const float*)d_in[5];
    const float* b3   = (const float*)d_in[6];
    const float* r1w1 = (const float*)d_in[7];
    const float* r1b1 = (const float*)d_in[8];
    const float* r1w2 = (const float*)d_in[9];
    const float* r1b2 = (const float*)d_in[10];
    const float* r2w1 = (const float*)d_in[11];
    const float* r2b1 = (const float*)d_in[12];
    const float* r2w2 = (const float*)d_in[13];
    const float* r2b2 = (const float*)d_in[14];
    const float* wpre = (const float*)d_in[15];
    const float* bpre = (const float*)d_in[16];
    const float* cb   = (const float*)d_in[17];
    float* out = (float*)d_out;

    float* ws   = (float*)d_ws;
    short* wsS  = (short*)d_ws;
    float* B = ws + B_OFF;
    float* A = ws + A_OFF;

    repack_all_k<<<1408, 256, 0, stream>>>(w2, w3, r1w1, r2w1, r1w2, r2w2, wsS);

    conv1_k<<<512, 256, 0, stream>>>(x,               w1, b1, A);
    mfma_conv<CfgConv2><<<512, 256, 0, stream>>>(A, wsS + W2_S, b2, B, 0);
    conv1_k<<<512, 256, 0, stream>>>(x + 8 * 65536,   w1, b1, A);
    mfma_conv<CfgConv2><<<512, 256, 0, stream>>>(A, wsS + W2_S, b2, B, 8);

    // conv3: B -> h @ A — 32x32x16 2-row kernel, partition fixed
    mfma_conv32<CfgConv3><<<512, 256, 0, stream>>>(B, wsS + W3_S, b3, A, 0);

    mfma_res<<<1024, 256, 0, stream>>>(A, wsS + WR1_S, r1b1, wsS + WP1_S, r1b2, B);
    mfma_res<<<1024, 256, 0, stream>>>(B, wsS + WR2_S, r2b1, wsS + WP2_S, r2b2, A);

    prevq_k<<<256, 256, 0, stream>>>(A, wpre, bpre, cb, out);
}